// Round 2
// 72.667 us; speedup vs baseline: 1.0092x; 1.0092x over previous
//
#include <hip/hip_runtime.h>

#define BB    256        // batch
#define TT    16384      // time
#define WIN   5
#define HID   5
#define NN    (TT - WIN)     // 16379 losses; NN-1 diffs/mask
#define TILE  32             // loss columns owned per block
#define NT    512            // TILE*NT = 16384 >= NN
#define LDSW  44             // staged row stride (>=40 cols), mult of 4 for b128
#define CH    64             // rows per chunk
#define NCH   4              // 4 chunks x 64 rows = 256 rows

// Fused kernel: losses + diffs + mask.
// v2: register double-buffered staging (T14): chunk c+1's global loads are
// issued before chunk c's compute, ds_write'd after it (vmcnt wait hidden
// under ~600 cyc of FMA). One barrier per 64-row chunk. Boundary column
// folded into the chunk loop (wave 0). Epilogue via wave-0 shfl (no Ls,
// one barrier fewer). LDS 27 KB (was 49.5).
__global__ __launch_bounds__(256)
void llsa_fused(const float* __restrict__ series,
                const float* __restrict__ weight,
                const float* __restrict__ bias,
                const float* __restrict__ thr_ptr,
                float* __restrict__ out) {
    const int tid = threadIdx.x;
    // XCD swizzle: XCD (p%8) owns a contiguous 64-tile (2048-col) span;
    // halo lines (cols 32..39 = neighbor's first line) become same-XCD L2 hits.
    const int t  = (blockIdx.x & 7) * 64 + (blockIdx.x >> 3);
    const int n0 = t * TILE;

    float w[HID][WIN], bi[HID];
#pragma unroll
    for (int h = 0; h < HID; ++h) {
        bi[h] = bias[h];
#pragma unroll
        for (int v = 0; v < WIN; ++v) w[h][v] = weight[h * WIN + v];
    }

    __shared__ float lds[2][CH * LDSW];    // 2 x 64 x 44 floats = 22.0 KB
    __shared__ float psum[32 * 33];        // padded: column reads conflict-free

    const int cq = tid & 7;                // column quad 0..7 (cols 4cq..4cq+3)
    const int rs = tid >> 3;               // row subgroup 0..31

    // ---- register staging (double-buffer) ----
    // A1: 64 rows x 8 quads (cols 0..31) = 2 float4/thread, coalesced
    //     (8 lanes x 128B contiguous per row).
    // A2: 64 rows x 2 quads (cols 32..39, halo) on tid<128.
    float4 ra0, ra1, rb;
    const int bcol = n0 + 32 + (tid & 1) * 4;        // A2 column
    const bool bok = (bcol + 3) < TT;                // false only on last tile

    auto GLOAD = [&](int c) {
        const int rbase = c * CH;
        ra0 = *(const float4*)(series + (size_t)(rbase + rs)      * TT + n0 + 4*cq);
        ra1 = *(const float4*)(series + (size_t)(rbase + 32 + rs) * TT + n0 + 4*cq);
        if (tid < 128) {
            rb = bok ? *(const float4*)(series + (size_t)(rbase + (tid >> 1)) * TT + bcol)
                     : make_float4(0.f, 0.f, 0.f, 0.f);
        }
    };
    auto SWRITE = [&](int b) {
        *(float4*)(&lds[b][(rs)      * LDSW + 4*cq]) = ra0;
        *(float4*)(&lds[b][(32 + rs) * LDSW + 4*cq]) = ra1;
        if (tid < 128) *(float4*)(&lds[b][(tid >> 1) * LDSW + 32 + (tid & 1) * 4]) = rb;
    };

    GLOAD(0); SWRITE(0);          // cold start: unavoidable stall
    GLOAD(1);                     // chunk 1 in flight during chunk 0 compute
    __syncthreads();

    float a0 = 0.f, a1 = 0.f, a2 = 0.f, a3 = 0.f, bacc = 0.f;

#pragma unroll
    for (int c = 0; c < NCH; ++c) {
        const int cur = c & 1;
        // ---- main: this thread's 2 rows of the chunk, cols 4cq..4cq+3 ----
#pragma unroll
        for (int it2 = 0; it2 < 2; ++it2) {
            const float* row = &lds[cur][(it2 * 32 + rs) * LDSW + 4 * cq];
            const float4 f0 = *(const float4*)(row);
            const float4 f1 = *(const float4*)(row + 4);
            const float4 f2 = *(const float4*)(row + 8);
            const float s[12] = { f0.x, f0.y, f0.z, f0.w,
                                  f1.x, f1.y, f1.z, f1.w,
                                  f2.x, f2.y, f2.z, f2.w };
#pragma unroll
            for (int j = 0; j < 4; ++j) {
                float aj = 0.f;
#pragma unroll
                for (int h = 0; h < HID; ++h) {
                    float tt = bi[h];
#pragma unroll
                    for (int v = 0; v < WIN; ++v) tt = fmaf(s[j + v], w[h][v], tt);
                    const float e = tt - s[j + h + 1];
                    aj = fmaf(e, e, aj);
                }
                if (j == 0) a0 += aj; else if (j == 1) a1 += aj;
                else if (j == 2) a2 += aj; else a3 += aj;
            }
        }
        // ---- boundary column n0+32 (halo): wave 0, local row = tid ----
        if (tid < 64) {
            const float* r2 = &lds[cur][tid * LDSW + 32];
            const float4 q0 = *(const float4*)(r2);
            const float2 q1 = *(const float2*)(r2 + 4);
            const float sv[6] = { q0.x, q0.y, q0.z, q0.w, q1.x, q1.y };
#pragma unroll
            for (int h = 0; h < HID; ++h) {
                float tt = bi[h];
#pragma unroll
                for (int v = 0; v < WIN; ++v) tt = fmaf(sv[v], w[h][v], tt);
                const float e = tt - sv[h + 1];
                bacc = fmaf(e, e, bacc);
            }
        }
        // ---- pipeline: write next chunk (loads already in flight), issue next-next
        if (c + 1 < NCH) {
            SWRITE((c + 1) & 1);
            if (c + 2 < NCH) GLOAD(c + 2);
        }
        __syncthreads();
    }

    // ---- boundary reduce across wave 0 (each lane holds 4 rows' worth) ----
    float bs = bacc;
#pragma unroll
    for (int off = 32; off >= 1; off >>= 1) bs += __shfl_down(bs, off);
    const float bL = __shfl(bs, 0);    // valid on wave 0 (the only consumer)

    // ---- reduce partials across row subgroups ----
    psum[rs * 33 + 4 * cq + 0] = a0;
    psum[rs * 33 + 4 * cq + 1] = a1;
    psum[rs * 33 + 4 * cq + 2] = a2;
    psum[rs * 33 + 4 * cq + 3] = a3;
    __syncthreads();

    if (tid < 32) {
        const float inv = 1.0f / (float)(BB * HID);
        float ssum = 0.f;
#pragma unroll
        for (int r = 0; r < 32; ++r) ssum += psum[r * 33 + tid];
        const float li = ssum * inv;
        float nx = __shfl_down(li, 1);         // neighbor loss (lane tid+1)
        if (tid == 31) nx = bL * inv;          // halo column loss
        const int i = n0 + tid;
        if (i < NN) {
            out[i] = li;
            if (i < NN - 1) {
                const float d = fabsf(nx - li);
                out[NN + i] = d;
                out[2 * NN - 1 + i] = (d > thr_ptr[0]) ? 1.0f : 0.0f;
            }
        }
    }
}

extern "C" void kernel_launch(void* const* d_in, const int* in_sizes, int n_in,
                              void* d_out, int out_size, void* d_ws, size_t ws_size,
                              hipStream_t stream) {
    const float* series = (const float*)d_in[0];
    const float* weight = (const float*)d_in[1];
    const float* bias   = (const float*)d_in[2];
    const float* thr    = (const float*)d_in[3];
    float* out = (float*)d_out;
    (void)d_ws; (void)ws_size; (void)in_sizes; (void)n_in; (void)out_size;

    llsa_fused<<<NT, 256, 0, stream>>>(series, weight, bias, thr, out);
}